// Round 5
// baseline (215.726 us; speedup 1.0000x reference)
//
#include <hip/hip_runtime.h>
#include <math.h>

// RPNLayer: logits = x(32768,1024) @ W(1024,16) + b; per-anchor (8) 2-class
// log-softmax CE over valid anchors; argmax + candidate mask.
//
// R5 structure: async global->LDS staging (global_load_lds width=16),
// wave-private slabs, barrier-free main loop.
//   - lane = row (64 rows/wave), wave ks owns K-slice [ks*128,(ks+1)*128).
//     W index wave-uniform -> scalar s_load pipe (kept from R4).
//   - x delivery: per 32-float chunk, 8x global_load_lds_dwordx4 stage
//     64 rows x 32 floats (8 KB) into this wave's slab. Async (vmcnt),
//     no VGPR round trip, 8x128B contiguous segments per instr.
//   - Swizzle (rule: linear dest + pre-swizzled SOURCE + swizzled READ):
//     lane's source k-quad tq = (lane&7)^(lane>>3); read col = t^(lane&7).
//     Spreads the 128B-stride row reads across all 32 banks (8-way = b128
//     data floor). Without it: 64 lanes on 4 banks = 8x LDS cost.
//   - Pipeline per chunk: vmcnt(0) [chunk ready] -> ds_read 8 quads ->
//     lgkmcnt(0) [slab free] -> issue next chunk's loads -> 512cy FMA.
//   - LDS 64KB/block -> 2 blocks/CU -> 16 waves/CU. ~70 VGPR, no spill.
//
// d_out (float32): [0] loss | [1..262144] predict | [262145..524288] mask

#define ROWS   64            // rows per block (= lanes per wave)
#define NW     8             // waves per block = K-split factor
#define KSLICE 128           // K per wave
#define CHUNK  32            // K floats per staged chunk
#define NCH    (KSLICE/CHUNK)   // 4
#define SLABF  (ROWS*CHUNK)  // 2048 floats = 8 KB per wave
#define RSTR   136           // reduction row stride: 8*16 + 8 pad

typedef __attribute__((address_space(3))) void       lds_v;
typedef const __attribute__((address_space(1))) void gbl_v;

__device__ __forceinline__ void stage16(const float* g, float* l)
{
    // 16B per lane, dest = wave-uniform base + lane*16 (linear)
    __builtin_amdgcn_global_load_lds((gbl_v*)g, (lds_v*)l, 16, 0, 0);
}

__global__ __launch_bounds__(512, 2)
void rpn_main(const float* __restrict__ x, const float* __restrict__ W,
              const float* __restrict__ b, const int* __restrict__ lab,
              float* __restrict__ out, float* __restrict__ ws)
{
    __shared__ float xs[NW * SLABF];         // 16384 floats = 65536 B
    float* red = xs;                         // aliased: lifetimes disjoint

    const int tid  = threadIdx.x;
    const int lane = tid & 63;
    const int ks   = __builtin_amdgcn_readfirstlane(tid >> 6);
    const int row0 = blockIdx.x * ROWS;

    const int rsub = lane >> 3;              // staging sub-row 0..7
    const int tq   = (lane & 7) ^ rsub;      // pre-swizzled source k-quad

    float* slab = xs + ks * SLABF;
    // staging source: row (row0 + rsub + i*8), k = ks*128 + ch*32 + tq*4
    const float* gstage = x + (size_t)(row0 + rsub) * 1024 + ks * KSLICE + tq * 4;
    const float* wk     = W + (size_t)(ks * KSLICE) * 16;

    float acc[16];
#pragma unroll
    for (int c = 0; c < 16; ++c) acc[c] = 0.f;

    // prologue: issue chunk 0's async stages
#pragma unroll
    for (int i = 0; i < 8; ++i)
        stage16(gstage + i * 8192, slab + i * 256);

#define FMA16(V, WROW)                                            \
    do {                                                          \
        const float* _w = (WROW);                                 \
        _Pragma("unroll")                                         \
        for (int c = 0; c < 16; ++c)                              \
            acc[c] = fmaf((V), _w[c], acc[c]);                    \
    } while (0)

#pragma unroll 1
    for (int ch = 0; ch < NCH; ++ch) {
        // chunk ch staged -> slab ready
        asm volatile("s_waitcnt vmcnt(0)" ::: "memory");
        __builtin_amdgcn_sched_barrier(0);

        // read this lane's 32 floats (8 swizzled b128 reads)
        float4 xq[8];
#pragma unroll
        for (int t = 0; t < 8; ++t)
            xq[t] = *(const float4*)(slab + lane * 32 + ((t ^ (lane & 7)) << 2));

        // slab free once reads complete; then issue next chunk's stages
        asm volatile("s_waitcnt lgkmcnt(0)" ::: "memory");
        __builtin_amdgcn_sched_barrier(0);
        if (ch + 1 < NCH) {
            const float* g = gstage + (ch + 1) * CHUNK;
#pragma unroll
            for (int i = 0; i < 8; ++i)
                stage16(g + i * 8192, slab + i * 256);
        }

        // FMAs cover the staging latency; W via wave-uniform scalar loads
        const float* wc = wk + (size_t)(ch * CHUNK) * 16;
#pragma unroll
        for (int t = 0; t < 8; ++t) {
            FMA16(xq[t].x, wc + (t * 4 + 0) * 16);
            FMA16(xq[t].y, wc + (t * 4 + 1) * 16);
            FMA16(xq[t].z, wc + (t * 4 + 2) * 16);
            FMA16(xq[t].w, wc + (t * 4 + 3) * 16);
        }
    }
#undef FMA16

    // ---- 8-way K reduction across waves via LDS (red aliases xs) ----
    __syncthreads();
    {
        float* rp = red + lane * RSTR + ks * 16;
        *(float4*)(rp + 0)  = make_float4(acc[0],  acc[1],  acc[2],  acc[3]);
        *(float4*)(rp + 4)  = make_float4(acc[4],  acc[5],  acc[6],  acc[7]);
        *(float4*)(rp + 8)  = make_float4(acc[8],  acc[9],  acc[10], acc[11]);
        *(float4*)(rp + 12) = make_float4(acc[12], acc[13], acc[14], acc[15]);
    }
    __syncthreads();

    // ---- epilogue: one thread per row (wave 0 only) ----
    if (tid < ROWS) {
        const int row = row0 + tid;
        float L[16];
#pragma unroll
        for (int c = 0; c < 16; ++c) {
            float s = 0.f;
#pragma unroll
            for (int k = 0; k < NW; ++k) s += red[tid * RSTR + k * 16 + c];
            L[c] = s + b[c];
        }

        const int* labp  = lab + (size_t)row * 8;
        float*     predp = out + 1 + (size_t)row * 8;
        float*     maskp = out + 1 + 262144 + (size_t)row * 8;

        float lsum = 0.f, lcnt = 0.f;
#pragma unroll
        for (int a = 0; a < 8; ++a) {
            float l0 = L[2 * a], l1 = L[2 * a + 1];
            int   lb = labp[a];
            int   pred  = (l1 > l0) ? 1 : 0;          // strict: tie -> class 0
            int   valid = (lb != -1);
            float m   = fmaxf(l0, l1);
            float lse = m + logf(expf(l0 - m) + expf(l1 - m));
            float nll = lse - ((lb == 1) ? l1 : l0);
            if (valid) { lsum += nll; lcnt += 1.f; }
            predp[a] = (float)pred;
            maskp[a] = (pred && valid) ? 1.f : 0.f;
        }

        // tid<64 == wave 0: full-wave shuffle reduction
#pragma unroll
        for (int off = 32; off > 0; off >>= 1) {
            lsum += __shfl_down(lsum, off, 64);
            lcnt += __shfl_down(lcnt, off, 64);
        }
        if (tid == 0) {
            atomicAdd(&ws[0], lsum);
            atomicAdd(&ws[1], lcnt);
        }
    }
}

__global__ void rpn_final(const float* __restrict__ ws, float* __restrict__ out)
{
    out[0] = ws[0] / fmaxf(ws[1], 1.f);
}

extern "C" void kernel_launch(void* const* d_in, const int* in_sizes, int n_in,
                              void* d_out, int out_size, void* d_ws, size_t ws_size,
                              hipStream_t stream)
{
    const float* x   = (const float*)d_in[0];   // (64,512,1024) f32
    const float* W   = (const float*)d_in[1];   // (1024,16) f32
    const float* b   = (const float*)d_in[2];   // (16,) f32
    const int*   lab = (const int*)d_in[3];     // (64,512,8) i32 in {-1,0,1}
    float* out = (float*)d_out;
    float* ws  = (float*)d_ws;

    hipMemsetAsync(ws, 0, 2 * sizeof(float), stream);
    rpn_main<<<dim3(512), dim3(512), 0, stream>>>(x, W, b, lab, out, ws);
    rpn_final<<<dim3(1), dim3(1), 0, stream>>>(ws, out);
}